// Round 1
// baseline (843.352 us; speedup 1.0000x reference)
//
#include <hip/hip_runtime.h>
#include <math.h>

#define HEADS 4
#define HID 32
#define D1 128

__device__ __forceinline__ float lrelu(float x){ return x > 0.f ? x : 0.2f*x; }
__device__ __forceinline__ float sel4(float a, float b, float c, float d, int h){
    return h==0 ? a : (h==1 ? b : (h==2 ? c : d));
}

// ---------------- CSR build ----------------

__global__ void hist_kernel(const int* __restrict__ ei, int E, int N, int* __restrict__ deg){
    int idx = blockIdx.x * blockDim.x + threadIdx.x;
    int total = E + N;
    if (idx >= total) return;
    int d = (idx < E) ? ei[E + idx] : (idx - E);   // dst row of edge_index, then self-loops
    atomicAdd(&deg[d], 1);
}

// single-block exclusive scan over deg[0..N-1] -> indptr[0..N], cursor copy
__global__ void scan_kernel(const int* __restrict__ deg, int* __restrict__ indptr,
                            int* __restrict__ cursor, int N){
    const int T = 1024;
    int tid = threadIdx.x;
    int chunk = (N + T - 1) / T;
    int base = tid * chunk;
    int s = 0;
    for (int i = 0; i < chunk; ++i){
        int idx = base + i;
        if (idx < N) s += deg[idx];
    }
    __shared__ int part[T];
    part[tid] = s;
    __syncthreads();
    for (int off = 1; off < T; off <<= 1){
        int v = (tid >= off) ? part[tid - off] : 0;
        __syncthreads();
        part[tid] += v;
        __syncthreads();
    }
    int run = (tid == 0) ? 0 : part[tid - 1];
    for (int i = 0; i < chunk; ++i){
        int idx = base + i;
        if (idx < N){
            indptr[idx] = run;
            cursor[idx] = run;
            run += deg[idx];
        }
    }
    if (tid == 0) indptr[N] = part[T - 1];
}

__global__ void scatter_kernel(const int* __restrict__ ei, int E, int N,
                               int* __restrict__ cursor, int* __restrict__ srcs){
    int idx = blockIdx.x * blockDim.x + threadIdx.x;
    if (idx >= E + N) return;
    int s, d;
    if (idx < E){ s = ei[idx]; d = ei[E + idx]; }
    else        { s = d = idx - E; }
    int pos = atomicAdd(&cursor[d], 1);
    srcs[pos] = s;
}

// ---------------- fused linear + attention coefficients ----------------
// xp[n][t] = sum_k in[n][k] * W[k][t]; als[n][h] = sum_c xp[n][h*32+c]*as[h][c]; same ald.
// 8 rows per 128-thread block.
__global__ __launch_bounds__(128) void linear_al(
        const float* __restrict__ in, const float* __restrict__ W,
        const float* __restrict__ as_, const float* __restrict__ ad_,
        float* __restrict__ xp, float* __restrict__ als, float* __restrict__ ald,
        int N, int K){
    __shared__ float hs[8 * 128];
    int t = threadIdx.x;
    int base = blockIdx.x * 8;
    int rows = N - base; if (rows > 8) rows = 8;
    for (int idx = t; idx < rows * K; idx += 128){
        int r = idx / K, k = idx - r * K;
        hs[r * K + k] = in[(size_t)(base + r) * K + k];
    }
    __syncthreads();
    float acc[8] = {0.f,0.f,0.f,0.f,0.f,0.f,0.f,0.f};
    for (int k = 0; k < K; ++k){
        float w = W[k * 128 + t];
        #pragma unroll
        for (int r = 0; r < 8; ++r) acc[r] += hs[r * K + k] * w;
    }
    float asv = as_[t], adv = ad_[t];
    for (int r = 0; r < rows; ++r){
        int row = base + r;
        float v = acc[r];
        xp[(size_t)row * 128 + t] = v;
        float vs = v * asv, vd = v * adv;
        #pragma unroll
        for (int m = 16; m >= 1; m >>= 1){
            vs += __shfl_xor(vs, m);
            vd += __shfl_xor(vd, m);
        }
        if ((t & 31) == 0){
            int h = t >> 5;
            als[row * 4 + h] = vs;
            ald[row * 4 + h] = vd;
        }
    }
}

// ---------------- per-node softmax aggregation ----------------
// one 128-thread block per dst node. mode=0: write h_out = elu(agg + b).
// mode=1: fuse classifier: out[n] = sigmoid(elu(agg+b) . cW + cb).
__global__ __launch_bounds__(128) void gat_agg(
        const float* __restrict__ xp, const float* __restrict__ als, const float* __restrict__ ald,
        const int* __restrict__ indptr, const int* __restrict__ srcs,
        const float* __restrict__ bias,
        float* __restrict__ hout, int N, int mode,
        const float* __restrict__ cW, const float* __restrict__ cb,
        float* __restrict__ fout){
    int n = blockIdx.x;
    int t = threadIdx.x;
    int beg = indptr[n], end = indptr[n + 1];
    float4 ad4 = ((const float4*)ald)[n];
    __shared__ float red[2][4];

    // pass 1: per-head max over incoming edges
    float lm0 = -INFINITY, lm1 = -INFINITY, lm2 = -INFINITY, lm3 = -INFINITY;
    for (int j = beg + t; j < end; j += 128){
        int s = srcs[j];
        float4 a4 = ((const float4*)als)[s];
        lm0 = fmaxf(lm0, lrelu(a4.x + ad4.x));
        lm1 = fmaxf(lm1, lrelu(a4.y + ad4.y));
        lm2 = fmaxf(lm2, lrelu(a4.z + ad4.z));
        lm3 = fmaxf(lm3, lrelu(a4.w + ad4.w));
    }
    #pragma unroll
    for (int m = 32; m >= 1; m >>= 1){
        lm0 = fmaxf(lm0, __shfl_xor(lm0, m));
        lm1 = fmaxf(lm1, __shfl_xor(lm1, m));
        lm2 = fmaxf(lm2, __shfl_xor(lm2, m));
        lm3 = fmaxf(lm3, __shfl_xor(lm3, m));
    }
    if ((t & 63) == 0){
        int w = t >> 6;
        red[w][0] = lm0; red[w][1] = lm1; red[w][2] = lm2; red[w][3] = lm3;
    }
    __syncthreads();
    float mh0 = fmaxf(red[0][0], red[1][0]);
    float mh1 = fmaxf(red[0][1], red[1][1]);
    float mh2 = fmaxf(red[0][2], red[1][2]);
    float mh3 = fmaxf(red[0][3], red[1][3]);
    __syncthreads();

    // pass 2: per-head sum of exp
    float ls0 = 0.f, ls1 = 0.f, ls2 = 0.f, ls3 = 0.f;
    for (int j = beg + t; j < end; j += 128){
        int s = srcs[j];
        float4 a4 = ((const float4*)als)[s];
        ls0 += expf(lrelu(a4.x + ad4.x) - mh0);
        ls1 += expf(lrelu(a4.y + ad4.y) - mh1);
        ls2 += expf(lrelu(a4.z + ad4.z) - mh2);
        ls3 += expf(lrelu(a4.w + ad4.w) - mh3);
    }
    #pragma unroll
    for (int m = 32; m >= 1; m >>= 1){
        ls0 += __shfl_xor(ls0, m);
        ls1 += __shfl_xor(ls1, m);
        ls2 += __shfl_xor(ls2, m);
        ls3 += __shfl_xor(ls3, m);
    }
    if ((t & 63) == 0){
        int w = t >> 6;
        red[w][0] = ls0; red[w][1] = ls1; red[w][2] = ls2; red[w][3] = ls3;
    }
    __syncthreads();
    float id0 = 1.f / (red[0][0] + red[1][0] + 1e-16f);
    float id1 = 1.f / (red[0][1] + red[1][1] + 1e-16f);
    float id2 = 1.f / (red[0][2] + red[1][2] + 1e-16f);
    float id3 = 1.f / (red[0][3] + red[1][3] + 1e-16f);

    // pass 3: weighted aggregation; thread t owns channel t, h = t>>5
    int h = t >> 5;
    float adh  = sel4(ad4.x, ad4.y, ad4.z, ad4.w, h);
    float mhh  = sel4(mh0, mh1, mh2, mh3, h);
    float invd = sel4(id0, id1, id2, id3, h);
    float acc = 0.f;
    for (int j = beg; j < end; ++j){
        int s = srcs[j];                          // uniform across block
        float4 a4 = ((const float4*)als)[s];      // broadcast
        float ash = sel4(a4.x, a4.y, a4.z, a4.w, h);
        float e = lrelu(ash + adh);
        float w = expf(e - mhh) * invd;
        acc += xp[(size_t)s * 128 + t] * w;       // coalesced 512B row gather
    }
    float v = acc + bias[t];
    v = v > 0.f ? v : (expf(v) - 1.f);            // ELU

    if (mode == 0){
        hout[(size_t)n * 128 + t] = v;
    } else {
        float p = v * cW[t];
        #pragma unroll
        for (int m = 32; m >= 1; m >>= 1) p += __shfl_xor(p, m);
        __syncthreads();
        if ((t & 63) == 0) red[t >> 6][0] = p;
        __syncthreads();
        if (t == 0){
            float logit = red[0][0] + red[1][0] + cb[0];
            fout[n] = 1.f / (1.f + expf(-logit));
        }
    }
}

extern "C" void kernel_launch(void* const* d_in, const int* in_sizes, int n_in,
                              void* d_out, int out_size, void* d_ws, size_t ws_size,
                              hipStream_t stream){
    const float* x   = (const float*)d_in[0];
    const int*   ei  = (const int*)d_in[1];
    const float* W1  = (const float*)d_in[2];
    const float* as1 = (const float*)d_in[3];
    const float* ad1 = (const float*)d_in[4];
    const float* b1  = (const float*)d_in[5];
    const float* W2  = (const float*)d_in[6];
    const float* as2 = (const float*)d_in[7];
    const float* ad2 = (const float*)d_in[8];
    const float* b2  = (const float*)d_in[9];
    const float* W3  = (const float*)d_in[10];
    const float* as3 = (const float*)d_in[11];
    const float* ad3 = (const float*)d_in[12];
    const float* b3  = (const float*)d_in[13];
    const float* cW  = (const float*)d_in[14];
    const float* cb  = (const float*)d_in[15];
    float* out = (float*)d_out;

    int N = in_sizes[0] / 3;
    int E = in_sizes[1] / 2;
    int EN = E + N;

    char* ws = (char*)d_ws;
    size_t off = 0;
    auto alloc = [&](size_t bytes) -> void* {
        void* p = ws + off;
        off += (bytes + 255) & ~(size_t)255;
        return p;
    };
    int*   deg    = (int*)alloc((size_t)N * 4);
    int*   cursor = (int*)alloc((size_t)N * 4);
    int*   indptr = (int*)alloc((size_t)(N + 1) * 4);
    int*   srcs   = (int*)alloc((size_t)EN * 4);
    float* XP     = (float*)alloc((size_t)N * 128 * 4);
    float* H      = (float*)alloc((size_t)N * 128 * 4);
    float* ALS    = (float*)alloc((size_t)N * 4 * 4);
    float* ALD    = (float*)alloc((size_t)N * 4 * 4);
    (void)ws_size;

    hipMemsetAsync(deg, 0, (size_t)N * 4, stream);
    hist_kernel<<<(EN + 255) / 256, 256, 0, stream>>>(ei, E, N, deg);
    scan_kernel<<<1, 1024, 0, stream>>>(deg, indptr, cursor, N);
    scatter_kernel<<<(EN + 255) / 256, 256, 0, stream>>>(ei, E, N, cursor, srcs);

    int lb = (N + 7) / 8;
    // layer 1 (K=3)
    linear_al<<<lb, 128, 0, stream>>>(x, W1, as1, ad1, XP, ALS, ALD, N, 3);
    gat_agg<<<N, 128, 0, stream>>>(XP, ALS, ALD, indptr, srcs, b1, H, N, 0, nullptr, nullptr, nullptr);
    // layer 2
    linear_al<<<lb, 128, 0, stream>>>(H, W2, as2, ad2, XP, ALS, ALD, N, 128);
    gat_agg<<<N, 128, 0, stream>>>(XP, ALS, ALD, indptr, srcs, b2, H, N, 0, nullptr, nullptr, nullptr);
    // layer 3 + fused classifier
    linear_al<<<lb, 128, 0, stream>>>(H, W3, as3, ad3, XP, ALS, ALD, N, 128);
    gat_agg<<<N, 128, 0, stream>>>(XP, ALS, ALD, indptr, srcs, b3, nullptr, N, 1, cW, cb, out);
}

// Round 2
// 545.148 us; speedup vs baseline: 1.5470x; 1.5470x over previous
//
#include <hip/hip_runtime.h>
#include <math.h>

__device__ __forceinline__ float lrelu(float x){ return x > 0.f ? x : 0.2f*x; }
__device__ __forceinline__ float sel4(float a, float b, float c, float d, int h){
    return h==0 ? a : (h==1 ? b : (h==2 ? c : d));
}
__device__ __forceinline__ float wmax(float v){
    #pragma unroll
    for (int m = 1; m < 64; m <<= 1) v = fmaxf(v, __shfl_xor(v, m));
    return v;
}
__device__ __forceinline__ float wsum(float v){
    #pragma unroll
    for (int m = 1; m < 64; m <<= 1) v += __shfl_xor(v, m);
    return v;
}

// ---------------- CSR build ----------------

__global__ void hist_kernel(const int* __restrict__ ei, int E, int N, int* __restrict__ deg){
    int idx = blockIdx.x * blockDim.x + threadIdx.x;
    if (idx >= E + N) return;
    int d = (idx < E) ? ei[E + idx] : (idx - E);
    atomicAdd(&deg[d], 1);
}

__global__ void scan_kernel(const int* __restrict__ deg, int* __restrict__ indptr,
                            int* __restrict__ cursor, int N){
    const int T = 1024;
    int tid = threadIdx.x;
    int chunk = (N + T - 1) / T;
    int base = tid * chunk;
    int s = 0;
    for (int i = 0; i < chunk; ++i){
        int idx = base + i;
        if (idx < N) s += deg[idx];
    }
    __shared__ int part[T];
    part[tid] = s;
    __syncthreads();
    for (int off = 1; off < T; off <<= 1){
        int v = (tid >= off) ? part[tid - off] : 0;
        __syncthreads();
        part[tid] += v;
        __syncthreads();
    }
    int run = (tid == 0) ? 0 : part[tid - 1];
    for (int i = 0; i < chunk; ++i){
        int idx = base + i;
        if (idx < N){
            indptr[idx] = run;
            cursor[idx] = run;
            run += deg[idx];
        }
    }
    if (tid == 0) indptr[N] = part[T - 1];
}

__global__ void scatter_kernel(const int* __restrict__ ei, int E, int N,
                               int* __restrict__ cursor, int* __restrict__ srcs){
    int idx = blockIdx.x * blockDim.x + threadIdx.x;
    if (idx >= E + N) return;
    int s, d;
    if (idx < E){ s = ei[idx]; d = ei[E + idx]; }
    else        { s = d = idx - E; }
    int pos = atomicAdd(&cursor[d], 1);
    srcs[pos] = s;
}

// ---------------- layer-1 linear (K=3) ----------------
__global__ __launch_bounds__(128) void linear_al(
        const float* __restrict__ in, const float* __restrict__ W,
        const float* __restrict__ as_, const float* __restrict__ ad_,
        float* __restrict__ xp, float* __restrict__ als, float* __restrict__ ald,
        int N, int K){
    __shared__ float hs[8 * 3];
    int t = threadIdx.x;
    int base = blockIdx.x * 8;
    int rows = N - base; if (rows > 8) rows = 8;
    for (int idx = t; idx < rows * K; idx += 128){
        int r = idx / K, k = idx - r * K;
        hs[r * K + k] = in[(size_t)(base + r) * K + k];
    }
    __syncthreads();
    float acc[8] = {0.f,0.f,0.f,0.f,0.f,0.f,0.f,0.f};
    for (int k = 0; k < K; ++k){
        float w = W[k * 128 + t];
        #pragma unroll
        for (int r = 0; r < 8; ++r) acc[r] += hs[r * K + k] * w;
    }
    float asv = as_[t], adv = ad_[t];
    for (int r = 0; r < rows; ++r){
        int row = base + r;
        float v = acc[r];
        xp[(size_t)row * 128 + t] = v;
        float vs = v * asv, vd = v * adv;
        #pragma unroll
        for (int m = 16; m >= 1; m >>= 1){
            vs += __shfl_xor(vs, m);
            vd += __shfl_xor(vd, m);
        }
        if ((t & 31) == 0){
            int h = t >> 5;
            als[row * 4 + h] = vs;
            ald[row * 4 + h] = vd;
        }
    }
}

// ---------------- K=128 linear: register-tiled fp32 GEMM + fused als/ald ----------------
// block = 256 threads, tile = 32 rows x 128 cols. thread: cg=t&31 (cols 4cg..4cg+3),
// rg=t>>5 (rows 4rg..4rg+3). 16 acc/thread, 1 ds_read_b128 per 16 FMA.
__global__ __launch_bounds__(256) void gemm128_al(
        const float* __restrict__ in, const float* __restrict__ W,
        const float* __restrict__ as_, const float* __restrict__ ad_,
        float* __restrict__ xp, float* __restrict__ als, float* __restrict__ ald,
        int N){
    __shared__ float Xs[32][128];
    int t = threadIdx.x;
    int base = blockIdx.x * 32;
    int rows = N - base; if (rows > 32) rows = 32;
    for (int f = t; f < 1024; f += 256){          // 1024 float4 = 32x128 floats
        int r = f >> 5, q = f & 31;
        float4 v = (r < rows) ? ((const float4*)(in + (size_t)(base + r) * 128))[q]
                              : make_float4(0.f,0.f,0.f,0.f);
        ((float4*)Xs)[f] = v;
    }
    __syncthreads();
    int cg = t & 31;
    int rg = t >> 5;
    float acc[4][4];
    #pragma unroll
    for (int i = 0; i < 4; ++i)
        #pragma unroll
        for (int j = 0; j < 4; ++j) acc[i][j] = 0.f;

    const float4* W4 = (const float4*)W;
    for (int k4 = 0; k4 < 32; ++k4){
        float4 w0 = W4[(4*k4+0)*32 + cg];
        float4 w1 = W4[(4*k4+1)*32 + cg];
        float4 w2 = W4[(4*k4+2)*32 + cg];
        float4 w3 = W4[(4*k4+3)*32 + cg];
        #pragma unroll
        for (int i = 0; i < 4; ++i){
            float4 xv = ((const float4*)(&Xs[4*rg + i][0]))[k4];
            acc[i][0] = fmaf(xv.x, w0.x, acc[i][0]);
            acc[i][0] = fmaf(xv.y, w1.x, acc[i][0]);
            acc[i][0] = fmaf(xv.z, w2.x, acc[i][0]);
            acc[i][0] = fmaf(xv.w, w3.x, acc[i][0]);
            acc[i][1] = fmaf(xv.x, w0.y, acc[i][1]);
            acc[i][1] = fmaf(xv.y, w1.y, acc[i][1]);
            acc[i][1] = fmaf(xv.z, w2.y, acc[i][1]);
            acc[i][1] = fmaf(xv.w, w3.y, acc[i][1]);
            acc[i][2] = fmaf(xv.x, w0.z, acc[i][2]);
            acc[i][2] = fmaf(xv.y, w1.z, acc[i][2]);
            acc[i][2] = fmaf(xv.z, w2.z, acc[i][2]);
            acc[i][2] = fmaf(xv.w, w3.z, acc[i][2]);
            acc[i][3] = fmaf(xv.x, w0.w, acc[i][3]);
            acc[i][3] = fmaf(xv.y, w1.w, acc[i][3]);
            acc[i][3] = fmaf(xv.z, w2.w, acc[i][3]);
            acc[i][3] = fmaf(xv.w, w3.w, acc[i][3]);
        }
    }

    float4 as4 = ((const float4*)as_)[cg];
    float4 ad4 = ((const float4*)ad_)[cg];
    #pragma unroll
    for (int i = 0; i < 4; ++i){
        int r = 4*rg + i;
        if (r < rows){
            int row = base + r;
            ((float4*)(xp + (size_t)row * 128))[cg] =
                make_float4(acc[i][0], acc[i][1], acc[i][2], acc[i][3]);
            float ps = acc[i][0]*as4.x + acc[i][1]*as4.y + acc[i][2]*as4.z + acc[i][3]*as4.w;
            float pd = acc[i][0]*ad4.x + acc[i][1]*ad4.y + acc[i][2]*ad4.z + acc[i][3]*ad4.w;
            ps += __shfl_xor(ps, 1); ps += __shfl_xor(ps, 2); ps += __shfl_xor(ps, 4);
            pd += __shfl_xor(pd, 1); pd += __shfl_xor(pd, 2); pd += __shfl_xor(pd, 4);
            if ((cg & 7) == 0){
                int h = cg >> 3;
                als[(size_t)row * 4 + h] = ps;
                ald[(size_t)row * 4 + h] = pd;
            }
        }
    }
}

// ---------------- per-node softmax aggregation: one WAVE per node ----------------
// 256-thr block = 4 waves = 4 nodes. lane l owns channels 2l,2l+1 (head h=l>>4).
// chunked (64 edges) online softmax; each expf computed exactly once, edge-parallel.
__global__ __launch_bounds__(256) void gat_agg2(
        const float* __restrict__ xp, const float4* __restrict__ als,
        const float4* __restrict__ ald,
        const int* __restrict__ indptr, const int* __restrict__ srcs,
        const float* __restrict__ bias,
        float* __restrict__ hout, int N, int mode,
        const float* __restrict__ cW, const float* __restrict__ cb,
        float* __restrict__ fout){
    int wid = threadIdx.x >> 6;
    int l   = threadIdx.x & 63;
    int n = blockIdx.x * 4 + wid;
    __shared__ int   ssh[4][64];
    __shared__ float esh[4][64][4];
    if (n >= N) return;

    int beg = indptr[n], end = indptr[n + 1];
    float4 ad4 = ald[n];
    int h = l >> 4;

    float m0 = -INFINITY, m1 = -INFINITY, m2 = -INFINITY, m3 = -INFINITY;
    float d0 = 0.f, d1 = 0.f, d2 = 0.f, d3 = 0.f;
    float ax = 0.f, ay = 0.f;

    for (int cbeg = beg; cbeg < end; cbeg += 64){
        int cnt = end - cbeg; if (cnt > 64) cnt = 64;
        float e0 = -INFINITY, e1 = -INFINITY, e2 = -INFINITY, e3 = -INFINITY;
        if (l < cnt){
            int s = srcs[cbeg + l];
            ssh[wid][l] = s;
            float4 a4 = als[s];
            e0 = lrelu(a4.x + ad4.x);
            e1 = lrelu(a4.y + ad4.y);
            e2 = lrelu(a4.z + ad4.z);
            e3 = lrelu(a4.w + ad4.w);
        }
        float c0 = wmax(e0), c1 = wmax(e1), c2 = wmax(e2), c3 = wmax(e3);
        float nm0 = fmaxf(m0, c0), nm1 = fmaxf(m1, c1);
        float nm2 = fmaxf(m2, c2), nm3 = fmaxf(m3, c3);
        float r0 = __expf(m0 - nm0), r1 = __expf(m1 - nm1);
        float r2 = __expf(m2 - nm2), r3 = __expf(m3 - nm3);
        d0 *= r0; d1 *= r1; d2 *= r2; d3 *= r3;
        float rh = sel4(r0, r1, r2, r3, h);
        ax *= rh; ay *= rh;
        m0 = nm0; m1 = nm1; m2 = nm2; m3 = nm3;

        float p0 = 0.f, p1 = 0.f, p2 = 0.f, p3 = 0.f;
        if (l < cnt){
            p0 = __expf(e0 - m0);
            p1 = __expf(e1 - m1);
            p2 = __expf(e2 - m2);
            p3 = __expf(e3 - m3);
            *((float4*)&esh[wid][l][0]) = make_float4(p0, p1, p2, p3);
        }
        d0 += wsum(p0); d1 += wsum(p1); d2 += wsum(p2); d3 += wsum(p3);

        for (int j = 0; j < cnt; ++j){
            int s = ssh[wid][j];
            float w = esh[wid][j][h];
            float2 xv = ((const float2*)(xp + (size_t)s * 128))[l];
            ax = fmaf(xv.x, w, ax);
            ay = fmaf(xv.y, w, ay);
        }
    }

    float dh = sel4(d0, d1, d2, d3, h);
    float inv = 1.f / (dh + 1e-16f);
    float2 b2 = ((const float2*)bias)[l];
    float vx = ax * inv + b2.x;
    float vy = ay * inv + b2.y;
    vx = vx > 0.f ? vx : (__expf(vx) - 1.f);
    vy = vy > 0.f ? vy : (__expf(vy) - 1.f);

    if (mode == 0){
        ((float2*)hout)[(size_t)n * 64 + l] = make_float2(vx, vy);
    } else {
        float2 cw2 = ((const float2*)cW)[l];
        float p = vx * cw2.x + vy * cw2.y;
        p = wsum(p);
        if (l == 0){
            float logit = p + cb[0];
            fout[n] = 1.f / (1.f + __expf(-logit));
        }
    }
}

extern "C" void kernel_launch(void* const* d_in, const int* in_sizes, int n_in,
                              void* d_out, int out_size, void* d_ws, size_t ws_size,
                              hipStream_t stream){
    const float* x   = (const float*)d_in[0];
    const int*   ei  = (const int*)d_in[1];
    const float* W1  = (const float*)d_in[2];
    const float* as1 = (const float*)d_in[3];
    const float* ad1 = (const float*)d_in[4];
    const float* b1  = (const float*)d_in[5];
    const float* W2  = (const float*)d_in[6];
    const float* as2 = (const float*)d_in[7];
    const float* ad2 = (const float*)d_in[8];
    const float* b2  = (const float*)d_in[9];
    const float* W3  = (const float*)d_in[10];
    const float* as3 = (const float*)d_in[11];
    const float* ad3 = (const float*)d_in[12];
    const float* b3  = (const float*)d_in[13];
    const float* cW  = (const float*)d_in[14];
    const float* cb  = (const float*)d_in[15];
    float* out = (float*)d_out;

    int N = in_sizes[0] / 3;
    int E = in_sizes[1] / 2;
    int EN = E + N;

    char* ws = (char*)d_ws;
    size_t off = 0;
    auto alloc = [&](size_t bytes) -> void* {
        void* p = ws + off;
        off += (bytes + 255) & ~(size_t)255;
        return p;
    };
    int*   deg    = (int*)alloc((size_t)N * 4);
    int*   cursor = (int*)alloc((size_t)N * 4);
    int*   indptr = (int*)alloc((size_t)(N + 1) * 4);
    int*   srcs   = (int*)alloc((size_t)EN * 4);
    float* XP     = (float*)alloc((size_t)N * 128 * 4);
    float* H      = (float*)alloc((size_t)N * 128 * 4);
    float* ALS    = (float*)alloc((size_t)N * 4 * 4);
    float* ALD    = (float*)alloc((size_t)N * 4 * 4);
    (void)ws_size;

    hipMemsetAsync(deg, 0, (size_t)N * 4, stream);
    hist_kernel<<<(EN + 255) / 256, 256, 0, stream>>>(ei, E, N, deg);
    scan_kernel<<<1, 1024, 0, stream>>>(deg, indptr, cursor, N);
    scatter_kernel<<<(EN + 255) / 256, 256, 0, stream>>>(ei, E, N, cursor, srcs);

    int ab = (N + 3) / 4;
    // layer 1 (K=3)
    linear_al<<<(N + 7) / 8, 128, 0, stream>>>(x, W1, as1, ad1, XP, ALS, ALD, N, 3);
    gat_agg2<<<ab, 256, 0, stream>>>(XP, (const float4*)ALS, (const float4*)ALD,
                                     indptr, srcs, b1, H, N, 0, nullptr, nullptr, nullptr);
    // layer 2
    gemm128_al<<<(N + 31) / 32, 256, 0, stream>>>(H, W2, as2, ad2, XP, ALS, ALD, N);
    gat_agg2<<<ab, 256, 0, stream>>>(XP, (const float4*)ALS, (const float4*)ALD,
                                     indptr, srcs, b2, H, N, 0, nullptr, nullptr, nullptr);
    // layer 3 + fused classifier
    gemm128_al<<<(N + 31) / 32, 256, 0, stream>>>(H, W3, as3, ad3, XP, ALS, ALD, N);
    gat_agg2<<<ab, 256, 0, stream>>>(XP, (const float4*)ALS, (const float4*)ALD,
                                     indptr, srcs, b3, nullptr, N, 1, cW, cb, out);
}

// Round 3
// 432.044 us; speedup vs baseline: 1.9520x; 1.2618x over previous
//
#include <hip/hip_runtime.h>
#include <math.h>

__device__ __forceinline__ float lrelu(float x){ return x > 0.f ? x : 0.2f*x; }
__device__ __forceinline__ float sel4(float a, float b, float c, float d, int h){
    return h==0 ? a : (h==1 ? b : (h==2 ? c : d));
}
__device__ __forceinline__ float wmax(float v){
    #pragma unroll
    for (int m = 1; m < 64; m <<= 1) v = fmaxf(v, __shfl_xor(v, m));
    return v;
}
__device__ __forceinline__ float wsum(float v){
    #pragma unroll
    for (int m = 1; m < 64; m <<= 1) v += __shfl_xor(v, m);
    return v;
}

// ---------------- CSR build ----------------

__global__ void hist_kernel(const int* __restrict__ ei, int E, int N, int* __restrict__ deg){
    int idx = blockIdx.x * blockDim.x + threadIdx.x;
    if (idx >= E + N) return;
    int d = (idx < E) ? ei[E + idx] : (idx - E);
    atomicAdd(&deg[d], 1);
}

// phase 1: per-1024-chunk sums
__global__ __launch_bounds__(256) void scan_blocksum(const int* __restrict__ deg,
                                                     int* __restrict__ bsum, int N){
    int b = blockIdx.x, t = threadIdx.x;
    int base = b * 1024 + t * 4;
    int s = 0;
    #pragma unroll
    for (int i = 0; i < 4; ++i){ int idx = base + i; if (idx < N) s += deg[idx]; }
    __shared__ int sm[256];
    sm[t] = s; __syncthreads();
    for (int off = 128; off > 0; off >>= 1){
        if (t < off) sm[t] += sm[t + off];
        __syncthreads();
    }
    if (t == 0) bsum[b] = sm[0];
}

// phase 2: exclusive scan of block sums (NB <= 1024), also writes indptr[N]=total
__global__ __launch_bounds__(1024) void scan_partials(int* __restrict__ bsum, int NB,
                                                      int* __restrict__ indptr, int N){
    int t = threadIdx.x;
    int v = (t < NB) ? bsum[t] : 0;
    __shared__ int sm[1024];
    sm[t] = v; __syncthreads();
    for (int off = 1; off < 1024; off <<= 1){
        int u = (t >= off) ? sm[t - off] : 0;
        __syncthreads();
        sm[t] += u;
        __syncthreads();
    }
    if (t < NB) bsum[t] = (t == 0) ? 0 : sm[t - 1];
    if (t == NB - 1) indptr[N] = sm[t];
}

// phase 3: local scan + block offset -> indptr, cursor
__global__ __launch_bounds__(256) void scan_final(const int* __restrict__ deg,
                                                  const int* __restrict__ bsum,
                                                  int* __restrict__ indptr,
                                                  int* __restrict__ cursor, int N){
    int b = blockIdx.x, t = threadIdx.x;
    int base = b * 1024 + t * 4;
    int v0 = 0, v1 = 0, v2 = 0, v3 = 0;
    if (base + 0 < N) v0 = deg[base + 0];
    if (base + 1 < N) v1 = deg[base + 1];
    if (base + 2 < N) v2 = deg[base + 2];
    if (base + 3 < N) v3 = deg[base + 3];
    int s = v0 + v1 + v2 + v3;
    __shared__ int sm[256];
    sm[t] = s; __syncthreads();
    for (int off = 1; off < 256; off <<= 1){
        int u = (t >= off) ? sm[t - off] : 0;
        __syncthreads();
        sm[t] += u;
        __syncthreads();
    }
    int run = bsum[b] + ((t == 0) ? 0 : sm[t - 1]);
    if (base + 0 < N){ indptr[base + 0] = run; cursor[base + 0] = run; run += v0; }
    if (base + 1 < N){ indptr[base + 1] = run; cursor[base + 1] = run; run += v1; }
    if (base + 2 < N){ indptr[base + 2] = run; cursor[base + 2] = run; run += v2; }
    if (base + 3 < N){ indptr[base + 3] = run; cursor[base + 3] = run; run += v3; }
}

__global__ void scatter_kernel(const int* __restrict__ ei, int E, int N,
                               int* __restrict__ cursor, int* __restrict__ srcs){
    int idx = blockIdx.x * blockDim.x + threadIdx.x;
    if (idx >= E + N) return;
    int s, d;
    if (idx < E){ s = ei[idx]; d = ei[E + idx]; }
    else        { s = d = idx - E; }
    int pos = atomicAdd(&cursor[d], 1);
    srcs[pos] = s;
}

// ---------------- layer-1 linear (K=3) ----------------
__global__ __launch_bounds__(128) void linear_al(
        const float* __restrict__ in, const float* __restrict__ W,
        const float* __restrict__ as_, const float* __restrict__ ad_,
        float* __restrict__ xp, float* __restrict__ als, float* __restrict__ ald,
        int N, int K){
    __shared__ float hs[8 * 3];
    int t = threadIdx.x;
    int base = blockIdx.x * 8;
    int rows = N - base; if (rows > 8) rows = 8;
    for (int idx = t; idx < rows * K; idx += 128){
        int r = idx / K, k = idx - r * K;
        hs[r * K + k] = in[(size_t)(base + r) * K + k];
    }
    __syncthreads();
    float acc[8] = {0.f,0.f,0.f,0.f,0.f,0.f,0.f,0.f};
    for (int k = 0; k < K; ++k){
        float w = W[k * 128 + t];
        #pragma unroll
        for (int r = 0; r < 8; ++r) acc[r] += hs[r * K + k] * w;
    }
    float asv = as_[t], adv = ad_[t];
    for (int r = 0; r < rows; ++r){
        int row = base + r;
        float v = acc[r];
        xp[(size_t)row * 128 + t] = v;
        float vs = v * asv, vd = v * adv;
        #pragma unroll
        for (int m = 16; m >= 1; m >>= 1){
            vs += __shfl_xor(vs, m);
            vd += __shfl_xor(vd, m);
        }
        if ((t & 31) == 0){
            int h = t >> 5;
            als[row * 4 + h] = vs;
            ald[row * 4 + h] = vd;
        }
    }
}

// ---------------- K=128 linear: register-tiled fp32 GEMM + fused als/ald ----------------
__global__ __launch_bounds__(256) void gemm128_al(
        const float* __restrict__ in, const float* __restrict__ W,
        const float* __restrict__ as_, const float* __restrict__ ad_,
        float* __restrict__ xp, float* __restrict__ als, float* __restrict__ ald,
        int N){
    __shared__ float Xs[32][128];
    int t = threadIdx.x;
    int base = blockIdx.x * 32;
    int rows = N - base; if (rows > 32) rows = 32;
    for (int f = t; f < 1024; f += 256){
        int r = f >> 5, q = f & 31;
        float4 v = (r < rows) ? ((const float4*)(in + (size_t)(base + r) * 128))[q]
                              : make_float4(0.f,0.f,0.f,0.f);
        ((float4*)Xs)[f] = v;
    }
    __syncthreads();
    int cg = t & 31;
    int rg = t >> 5;
    float acc[4][4];
    #pragma unroll
    for (int i = 0; i < 4; ++i)
        #pragma unroll
        for (int j = 0; j < 4; ++j) acc[i][j] = 0.f;

    const float4* W4 = (const float4*)W;
    for (int k4 = 0; k4 < 32; ++k4){
        float4 w0 = W4[(4*k4+0)*32 + cg];
        float4 w1 = W4[(4*k4+1)*32 + cg];
        float4 w2 = W4[(4*k4+2)*32 + cg];
        float4 w3 = W4[(4*k4+3)*32 + cg];
        #pragma unroll
        for (int i = 0; i < 4; ++i){
            float4 xv = ((const float4*)(&Xs[4*rg + i][0]))[k4];
            acc[i][0] = fmaf(xv.x, w0.x, acc[i][0]);
            acc[i][0] = fmaf(xv.y, w1.x, acc[i][0]);
            acc[i][0] = fmaf(xv.z, w2.x, acc[i][0]);
            acc[i][0] = fmaf(xv.w, w3.x, acc[i][0]);
            acc[i][1] = fmaf(xv.x, w0.y, acc[i][1]);
            acc[i][1] = fmaf(xv.y, w1.y, acc[i][1]);
            acc[i][1] = fmaf(xv.z, w2.y, acc[i][1]);
            acc[i][1] = fmaf(xv.w, w3.y, acc[i][1]);
            acc[i][2] = fmaf(xv.x, w0.z, acc[i][2]);
            acc[i][2] = fmaf(xv.y, w1.z, acc[i][2]);
            acc[i][2] = fmaf(xv.z, w2.z, acc[i][2]);
            acc[i][2] = fmaf(xv.w, w3.z, acc[i][2]);
            acc[i][3] = fmaf(xv.x, w0.w, acc[i][3]);
            acc[i][3] = fmaf(xv.y, w1.w, acc[i][3]);
            acc[i][3] = fmaf(xv.z, w2.w, acc[i][3]);
            acc[i][3] = fmaf(xv.w, w3.w, acc[i][3]);
        }
    }

    float4 as4 = ((const float4*)as_)[cg];
    float4 ad4 = ((const float4*)ad_)[cg];
    #pragma unroll
    for (int i = 0; i < 4; ++i){
        int r = 4*rg + i;
        if (r < rows){
            int row = base + r;
            ((float4*)(xp + (size_t)row * 128))[cg] =
                make_float4(acc[i][0], acc[i][1], acc[i][2], acc[i][3]);
            float ps = acc[i][0]*as4.x + acc[i][1]*as4.y + acc[i][2]*as4.z + acc[i][3]*as4.w;
            float pd = acc[i][0]*ad4.x + acc[i][1]*ad4.y + acc[i][2]*ad4.z + acc[i][3]*ad4.w;
            ps += __shfl_xor(ps, 1); ps += __shfl_xor(ps, 2); ps += __shfl_xor(ps, 4);
            pd += __shfl_xor(pd, 1); pd += __shfl_xor(pd, 2); pd += __shfl_xor(pd, 4);
            if ((cg & 7) == 0){
                int h = cg >> 3;
                als[(size_t)row * 4 + h] = ps;
                ald[(size_t)row * 4 + h] = pd;
            }
        }
    }
}

// ---------------- per-node softmax aggregation: one WAVE per node ----------------
__global__ __launch_bounds__(256) void gat_agg2(
        const float* __restrict__ xp, const float4* __restrict__ als,
        const float4* __restrict__ ald,
        const int* __restrict__ indptr, const int* __restrict__ srcs,
        const float* __restrict__ bias,
        float* __restrict__ hout, int N, int mode,
        const float* __restrict__ cW, const float* __restrict__ cb,
        float* __restrict__ fout){
    int wid = threadIdx.x >> 6;
    int l   = threadIdx.x & 63;
    int n = blockIdx.x * 4 + wid;
    __shared__ int   ssh[4][64];
    __shared__ float esh[4][64][4];
    if (n >= N) return;

    int beg = indptr[n], end = indptr[n + 1];
    float4 ad4 = ald[n];
    int h = l >> 4;

    float m0 = -INFINITY, m1 = -INFINITY, m2 = -INFINITY, m3 = -INFINITY;
    float d0 = 0.f, d1 = 0.f, d2 = 0.f, d3 = 0.f;
    float ax = 0.f, ay = 0.f;

    for (int cbeg = beg; cbeg < end; cbeg += 64){
        int cnt = end - cbeg; if (cnt > 64) cnt = 64;
        float e0 = -INFINITY, e1 = -INFINITY, e2 = -INFINITY, e3 = -INFINITY;
        if (l < cnt){
            int s = srcs[cbeg + l];
            ssh[wid][l] = s;
            float4 a4 = als[s];
            e0 = lrelu(a4.x + ad4.x);
            e1 = lrelu(a4.y + ad4.y);
            e2 = lrelu(a4.z + ad4.z);
            e3 = lrelu(a4.w + ad4.w);
        }
        float c0 = wmax(e0), c1 = wmax(e1), c2 = wmax(e2), c3 = wmax(e3);
        float nm0 = fmaxf(m0, c0), nm1 = fmaxf(m1, c1);
        float nm2 = fmaxf(m2, c2), nm3 = fmaxf(m3, c3);
        float r0 = __expf(m0 - nm0), r1 = __expf(m1 - nm1);
        float r2 = __expf(m2 - nm2), r3 = __expf(m3 - nm3);
        d0 *= r0; d1 *= r1; d2 *= r2; d3 *= r3;
        float rh = sel4(r0, r1, r2, r3, h);
        ax *= rh; ay *= rh;
        m0 = nm0; m1 = nm1; m2 = nm2; m3 = nm3;

        float p0 = 0.f, p1 = 0.f, p2 = 0.f, p3 = 0.f;
        if (l < cnt){
            p0 = __expf(e0 - m0);
            p1 = __expf(e1 - m1);
            p2 = __expf(e2 - m2);
            p3 = __expf(e3 - m3);
            *((float4*)&esh[wid][l][0]) = make_float4(p0, p1, p2, p3);
        }
        d0 += wsum(p0); d1 += wsum(p1); d2 += wsum(p2); d3 += wsum(p3);

        for (int j = 0; j < cnt; ++j){
            int s = ssh[wid][j];
            float w = esh[wid][j][h];
            float2 xv = ((const float2*)(xp + (size_t)s * 128))[l];
            ax = fmaf(xv.x, w, ax);
            ay = fmaf(xv.y, w, ay);
        }
    }

    float dh = sel4(d0, d1, d2, d3, h);
    float inv = 1.f / (dh + 1e-16f);
    float2 b2 = ((const float2*)bias)[l];
    float vx = ax * inv + b2.x;
    float vy = ay * inv + b2.y;
    vx = vx > 0.f ? vx : (__expf(vx) - 1.f);
    vy = vy > 0.f ? vy : (__expf(vy) - 1.f);

    if (mode == 0){
        ((float2*)hout)[(size_t)n * 64 + l] = make_float2(vx, vy);
    } else {
        float2 cw2 = ((const float2*)cW)[l];
        float p = vx * cw2.x + vy * cw2.y;
        p = wsum(p);
        if (l == 0){
            float logit = p + cb[0];
            fout[n] = 1.f / (1.f + __expf(-logit));
        }
    }
}

extern "C" void kernel_launch(void* const* d_in, const int* in_sizes, int n_in,
                              void* d_out, int out_size, void* d_ws, size_t ws_size,
                              hipStream_t stream){
    const float* x   = (const float*)d_in[0];
    const int*   ei  = (const int*)d_in[1];
    const float* W1  = (const float*)d_in[2];
    const float* as1 = (const float*)d_in[3];
    const float* ad1 = (const float*)d_in[4];
    const float* b1  = (const float*)d_in[5];
    const float* W2  = (const float*)d_in[6];
    const float* as2 = (const float*)d_in[7];
    const float* ad2 = (const float*)d_in[8];
    const float* b2  = (const float*)d_in[9];
    const float* W3  = (const float*)d_in[10];
    const float* as3 = (const float*)d_in[11];
    const float* ad3 = (const float*)d_in[12];
    const float* b3  = (const float*)d_in[13];
    const float* cW  = (const float*)d_in[14];
    const float* cb  = (const float*)d_in[15];
    float* out = (float*)d_out;

    int N = in_sizes[0] / 3;
    int E = in_sizes[1] / 2;
    int EN = E + N;

    char* ws = (char*)d_ws;
    size_t off = 0;
    auto alloc = [&](size_t bytes) -> void* {
        void* p = ws + off;
        off += (bytes + 255) & ~(size_t)255;
        return p;
    };
    int*   deg    = (int*)alloc((size_t)N * 4);
    int*   cursor = (int*)alloc((size_t)N * 4);
    int*   indptr = (int*)alloc((size_t)(N + 1) * 4);
    int*   srcs   = (int*)alloc((size_t)EN * 4);
    float* XP     = (float*)alloc((size_t)N * 128 * 4);
    float* H      = (float*)alloc((size_t)N * 128 * 4);
    float* ALS    = (float*)alloc((size_t)N * 4 * 4);
    float* ALD    = (float*)alloc((size_t)N * 4 * 4);
    int*   bsum   = (int*)alloc((size_t)1024 * 4);
    (void)ws_size;

    int NB = (N + 1023) / 1024;   // <= 1024 (N <= 1M)

    hipMemsetAsync(deg, 0, (size_t)N * 4, stream);
    hist_kernel<<<(EN + 255) / 256, 256, 0, stream>>>(ei, E, N, deg);
    scan_blocksum<<<NB, 256, 0, stream>>>(deg, bsum, N);
    scan_partials<<<1, 1024, 0, stream>>>(bsum, NB, indptr, N);
    scan_final<<<NB, 256, 0, stream>>>(deg, bsum, indptr, cursor, N);
    scatter_kernel<<<(EN + 255) / 256, 256, 0, stream>>>(ei, E, N, cursor, srcs);

    int ab = (N + 3) / 4;
    // layer 1 (K=3)
    linear_al<<<(N + 7) / 8, 128, 0, stream>>>(x, W1, as1, ad1, XP, ALS, ALD, N, 3);
    gat_agg2<<<ab, 256, 0, stream>>>(XP, (const float4*)ALS, (const float4*)ALD,
                                     indptr, srcs, b1, H, N, 0, nullptr, nullptr, nullptr);
    // layer 2
    gemm128_al<<<(N + 31) / 32, 256, 0, stream>>>(H, W2, as2, ad2, XP, ALS, ALD, N);
    gat_agg2<<<ab, 256, 0, stream>>>(XP, (const float4*)ALS, (const float4*)ALD,
                                     indptr, srcs, b2, H, N, 0, nullptr, nullptr, nullptr);
    // layer 3 + fused classifier
    gemm128_al<<<(N + 31) / 32, 256, 0, stream>>>(H, W3, as3, ad3, XP, ALS, ALD, N);
    gat_agg2<<<ab, 256, 0, stream>>>(XP, (const float4*)ALS, (const float4*)ALD,
                                     indptr, srcs, b3, nullptr, N, 1, cW, cb, out);
}

// Round 4
// 342.353 us; speedup vs baseline: 2.4634x; 1.2620x over previous
//
#include <hip/hip_runtime.h>
#include <math.h>

typedef unsigned int uint_t;

__device__ __forceinline__ float lrelu(float x){ return x > 0.f ? x : 0.2f*x; }
__device__ __forceinline__ float sel4(float a, float b, float c, float d, int h){
    return h==0 ? a : (h==1 ? b : (h==2 ? c : d));
}
__device__ __forceinline__ float wmax(float v){
    #pragma unroll
    for (int m = 1; m < 64; m <<= 1) v = fmaxf(v, __shfl_xor(v, m));
    return v;
}
__device__ __forceinline__ float wsum(float v){
    #pragma unroll
    for (int m = 1; m < 64; m <<= 1) v += __shfl_xor(v, m);
    return v;
}
// pack two floats to bf16x2 (RNE), lo = a (even channel), hi = b (odd channel)
__device__ __forceinline__ uint_t pack_bf2(float a, float b){
    uint_t ua = __float_as_uint(a); uint_t ub = __float_as_uint(b);
    ua += 0x7FFFu + ((ua >> 16) & 1u);
    ub += 0x7FFFu + ((ub >> 16) & 1u);
    return (ua >> 16) | (ub & 0xFFFF0000u);
}

// ---------------- CSR build ----------------

__global__ void hist_kernel(const int* __restrict__ ei, int E, int N, int* __restrict__ deg){
    int idx = blockIdx.x * blockDim.x + threadIdx.x;
    if (idx >= E + N) return;
    int d = (idx < E) ? ei[E + idx] : (idx - E);
    atomicAdd(&deg[d], 1);
}

__global__ __launch_bounds__(256) void scan_blocksum(const int* __restrict__ deg,
                                                     int* __restrict__ bsum, int N){
    int b = blockIdx.x, t = threadIdx.x;
    int base = b * 1024 + t * 4;
    int s = 0;
    #pragma unroll
    for (int i = 0; i < 4; ++i){ int idx = base + i; if (idx < N) s += deg[idx]; }
    __shared__ int sm[256];
    sm[t] = s; __syncthreads();
    for (int off = 128; off > 0; off >>= 1){
        if (t < off) sm[t] += sm[t + off];
        __syncthreads();
    }
    if (t == 0) bsum[b] = sm[0];
}

__global__ __launch_bounds__(1024) void scan_partials(int* __restrict__ bsum, int NB,
                                                      int* __restrict__ indptr, int N){
    int t = threadIdx.x;
    int v = (t < NB) ? bsum[t] : 0;
    __shared__ int sm[1024];
    sm[t] = v; __syncthreads();
    for (int off = 1; off < 1024; off <<= 1){
        int u = (t >= off) ? sm[t - off] : 0;
        __syncthreads();
        sm[t] += u;
        __syncthreads();
    }
    if (t < NB) bsum[t] = (t == 0) ? 0 : sm[t - 1];
    if (t == NB - 1) indptr[N] = sm[t];
}

__global__ __launch_bounds__(256) void scan_final(const int* __restrict__ deg,
                                                  const int* __restrict__ bsum,
                                                  int* __restrict__ indptr,
                                                  int* __restrict__ cursor, int N){
    int b = blockIdx.x, t = threadIdx.x;
    int base = b * 1024 + t * 4;
    int v0 = 0, v1 = 0, v2 = 0, v3 = 0;
    if (base + 0 < N) v0 = deg[base + 0];
    if (base + 1 < N) v1 = deg[base + 1];
    if (base + 2 < N) v2 = deg[base + 2];
    if (base + 3 < N) v3 = deg[base + 3];
    int s = v0 + v1 + v2 + v3;
    __shared__ int sm[256];
    sm[t] = s; __syncthreads();
    for (int off = 1; off < 256; off <<= 1){
        int u = (t >= off) ? sm[t - off] : 0;
        __syncthreads();
        sm[t] += u;
        __syncthreads();
    }
    int run = bsum[b] + ((t == 0) ? 0 : sm[t - 1]);
    if (base + 0 < N){ indptr[base + 0] = run; cursor[base + 0] = run; run += v0; }
    if (base + 1 < N){ indptr[base + 1] = run; cursor[base + 1] = run; run += v1; }
    if (base + 2 < N){ indptr[base + 2] = run; cursor[base + 2] = run; run += v2; }
    if (base + 3 < N){ indptr[base + 3] = run; cursor[base + 3] = run; run += v3; }
}

__global__ void scatter_kernel(const int* __restrict__ ei, int E, int N,
                               int* __restrict__ cursor, int* __restrict__ srcs){
    int idx = blockIdx.x * blockDim.x + threadIdx.x;
    if (idx >= E + N) return;
    int s, d;
    if (idx < E){ s = ei[idx]; d = ei[E + idx]; }
    else        { s = d = idx - E; }
    int pos = atomicAdd(&cursor[d], 1);
    srcs[pos] = s;
}

// ---------------- layer-1 linear (K=3): xp packed bf16x2 ----------------
__global__ __launch_bounds__(128) void linear_al(
        const float* __restrict__ in, const float* __restrict__ W,
        const float* __restrict__ as_, const float* __restrict__ ad_,
        uint_t* __restrict__ xp16, float* __restrict__ als, float* __restrict__ ald,
        int N, int K){
    __shared__ float hs[8 * 3];
    int t = threadIdx.x;
    int base = blockIdx.x * 8;
    int rows = N - base; if (rows > 8) rows = 8;
    for (int idx = t; idx < rows * K; idx += 128){
        int r = idx / K, k = idx - r * K;
        hs[r * K + k] = in[(size_t)(base + r) * K + k];
    }
    __syncthreads();
    float acc[8] = {0.f,0.f,0.f,0.f,0.f,0.f,0.f,0.f};
    for (int k = 0; k < K; ++k){
        float w = W[k * 128 + t];
        #pragma unroll
        for (int r = 0; r < 8; ++r) acc[r] += hs[r * K + k] * w;
    }
    float asv = as_[t], adv = ad_[t];
    for (int r = 0; r < rows; ++r){
        int row = base + r;
        float v = acc[r];
        float vo = __shfl_xor(v, 1);              // neighbor channel value
        if (!(t & 1)) xp16[(size_t)row * 64 + (t >> 1)] = pack_bf2(v, vo);
        float vs = v * asv, vd = v * adv;
        #pragma unroll
        for (int m = 16; m >= 1; m >>= 1){
            vs += __shfl_xor(vs, m);
            vd += __shfl_xor(vd, m);
        }
        if ((t & 31) == 0){
            int h = t >> 5;
            als[row * 4 + h] = vs;
            ald[row * 4 + h] = vd;
        }
    }
}

// ---------------- K=128 linear: register-tiled fp32 GEMM + fused als/ald ----------------
__global__ __launch_bounds__(256) void gemm128_al(
        const float* __restrict__ in, const float* __restrict__ W,
        const float* __restrict__ as_, const float* __restrict__ ad_,
        uint_t* __restrict__ xp16, float* __restrict__ als, float* __restrict__ ald,
        int N){
    __shared__ float Xs[32][128];
    int t = threadIdx.x;
    int base = blockIdx.x * 32;
    int rows = N - base; if (rows > 32) rows = 32;
    for (int f = t; f < 1024; f += 256){
        int r = f >> 5, q = f & 31;
        float4 v = (r < rows) ? ((const float4*)(in + (size_t)(base + r) * 128))[q]
                              : make_float4(0.f,0.f,0.f,0.f);
        ((float4*)Xs)[f] = v;
    }
    __syncthreads();
    int cg = t & 31;
    int rg = t >> 5;
    float acc[4][4];
    #pragma unroll
    for (int i = 0; i < 4; ++i)
        #pragma unroll
        for (int j = 0; j < 4; ++j) acc[i][j] = 0.f;

    const float4* W4 = (const float4*)W;
    for (int k4 = 0; k4 < 32; ++k4){
        float4 w0 = W4[(4*k4+0)*32 + cg];
        float4 w1 = W4[(4*k4+1)*32 + cg];
        float4 w2 = W4[(4*k4+2)*32 + cg];
        float4 w3 = W4[(4*k4+3)*32 + cg];
        #pragma unroll
        for (int i = 0; i < 4; ++i){
            float4 xv = ((const float4*)(&Xs[4*rg + i][0]))[k4];
            acc[i][0] = fmaf(xv.x, w0.x, acc[i][0]);
            acc[i][0] = fmaf(xv.y, w1.x, acc[i][0]);
            acc[i][0] = fmaf(xv.z, w2.x, acc[i][0]);
            acc[i][0] = fmaf(xv.w, w3.x, acc[i][0]);
            acc[i][1] = fmaf(xv.x, w0.y, acc[i][1]);
            acc[i][1] = fmaf(xv.y, w1.y, acc[i][1]);
            acc[i][1] = fmaf(xv.z, w2.y, acc[i][1]);
            acc[i][1] = fmaf(xv.w, w3.y, acc[i][1]);
            acc[i][2] = fmaf(xv.x, w0.z, acc[i][2]);
            acc[i][2] = fmaf(xv.y, w1.z, acc[i][2]);
            acc[i][2] = fmaf(xv.z, w2.z, acc[i][2]);
            acc[i][2] = fmaf(xv.w, w3.z, acc[i][2]);
            acc[i][3] = fmaf(xv.x, w0.w, acc[i][3]);
            acc[i][3] = fmaf(xv.y, w1.w, acc[i][3]);
            acc[i][3] = fmaf(xv.z, w2.w, acc[i][3]);
            acc[i][3] = fmaf(xv.w, w3.w, acc[i][3]);
        }
    }

    float4 as4 = ((const float4*)as_)[cg];
    float4 ad4 = ((const float4*)ad_)[cg];
    #pragma unroll
    for (int i = 0; i < 4; ++i){
        int r = 4*rg + i;
        if (r < rows){
            int row = base + r;
            uint2 pk;
            pk.x = pack_bf2(acc[i][0], acc[i][1]);
            pk.y = pack_bf2(acc[i][2], acc[i][3]);
            ((uint2*)xp16)[(size_t)row * 32 + cg] = pk;
            float ps = acc[i][0]*as4.x + acc[i][1]*as4.y + acc[i][2]*as4.z + acc[i][3]*as4.w;
            float pd = acc[i][0]*ad4.x + acc[i][1]*ad4.y + acc[i][2]*ad4.z + acc[i][3]*ad4.w;
            ps += __shfl_xor(ps, 1); ps += __shfl_xor(ps, 2); ps += __shfl_xor(ps, 4);
            pd += __shfl_xor(pd, 1); pd += __shfl_xor(pd, 2); pd += __shfl_xor(pd, 4);
            if ((cg & 7) == 0){
                int h = cg >> 3;
                als[(size_t)row * 4 + h] = ps;
                ald[(size_t)row * 4 + h] = pd;
            }
        }
    }
}

// ---------------- per-node softmax aggregation: one WAVE per node ----------------
// lane l owns channels 2l,2l+1 (head h=l>>4). xp gather in packed bf16x2, unroll x4.
__global__ __launch_bounds__(256) void gat_agg2(
        const uint_t* __restrict__ xp16, const float4* __restrict__ als,
        const float4* __restrict__ ald,
        const int* __restrict__ indptr, const int* __restrict__ srcs,
        const float* __restrict__ bias,
        float* __restrict__ hout, int N, int mode,
        const float* __restrict__ cW, const float* __restrict__ cb,
        float* __restrict__ fout){
    int wid = threadIdx.x >> 6;
    int l   = threadIdx.x & 63;
    int n = blockIdx.x * 4 + wid;
    __shared__ int   ssh[4][64];
    __shared__ float esh[4][64][4];
    if (n >= N) return;

    int beg = indptr[n], end = indptr[n + 1];
    float4 ad4 = ald[n];
    int h = l >> 4;

    float m0 = -INFINITY, m1 = -INFINITY, m2 = -INFINITY, m3 = -INFINITY;
    float d0 = 0.f, d1 = 0.f, d2 = 0.f, d3 = 0.f;
    float ax = 0.f, ay = 0.f;

    for (int cbeg = beg; cbeg < end; cbeg += 64){
        int cnt = end - cbeg; if (cnt > 64) cnt = 64;
        float e0 = -INFINITY, e1 = -INFINITY, e2 = -INFINITY, e3 = -INFINITY;
        if (l < cnt){
            int s = srcs[cbeg + l];
            ssh[wid][l] = s;
            float4 a4 = als[s];
            e0 = lrelu(a4.x + ad4.x);
            e1 = lrelu(a4.y + ad4.y);
            e2 = lrelu(a4.z + ad4.z);
            e3 = lrelu(a4.w + ad4.w);
        }
        float c0 = wmax(e0), c1 = wmax(e1), c2 = wmax(e2), c3 = wmax(e3);
        float nm0 = fmaxf(m0, c0), nm1 = fmaxf(m1, c1);
        float nm2 = fmaxf(m2, c2), nm3 = fmaxf(m3, c3);
        float r0 = __expf(m0 - nm0), r1 = __expf(m1 - nm1);
        float r2 = __expf(m2 - nm2), r3 = __expf(m3 - nm3);
        d0 *= r0; d1 *= r1; d2 *= r2; d3 *= r3;
        float rh = sel4(r0, r1, r2, r3, h);
        ax *= rh; ay *= rh;
        m0 = nm0; m1 = nm1; m2 = nm2; m3 = nm3;

        float p0 = 0.f, p1 = 0.f, p2 = 0.f, p3 = 0.f;
        if (l < cnt){
            p0 = __expf(e0 - m0);
            p1 = __expf(e1 - m1);
            p2 = __expf(e2 - m2);
            p3 = __expf(e3 - m3);
            *((float4*)&esh[wid][l][0]) = make_float4(p0, p1, p2, p3);
        }
        d0 += wsum(p0); d1 += wsum(p1); d2 += wsum(p2); d3 += wsum(p3);

        int j = 0;
        for (; j + 4 <= cnt; j += 4){
            int s0 = ssh[wid][j+0]; float w0 = esh[wid][j+0][h];
            int s1 = ssh[wid][j+1]; float w1 = esh[wid][j+1][h];
            int s2 = ssh[wid][j+2]; float w2 = esh[wid][j+2][h];
            int s3 = ssh[wid][j+3]; float w3 = esh[wid][j+3][h];
            uint_t u0 = xp16[(size_t)s0 * 64 + l];
            uint_t u1 = xp16[(size_t)s1 * 64 + l];
            uint_t u2 = xp16[(size_t)s2 * 64 + l];
            uint_t u3 = xp16[(size_t)s3 * 64 + l];
            ax = fmaf(__uint_as_float(u0 << 16), w0, ax);
            ay = fmaf(__uint_as_float(u0 & 0xFFFF0000u), w0, ay);
            ax = fmaf(__uint_as_float(u1 << 16), w1, ax);
            ay = fmaf(__uint_as_float(u1 & 0xFFFF0000u), w1, ay);
            ax = fmaf(__uint_as_float(u2 << 16), w2, ax);
            ay = fmaf(__uint_as_float(u2 & 0xFFFF0000u), w2, ay);
            ax = fmaf(__uint_as_float(u3 << 16), w3, ax);
            ay = fmaf(__uint_as_float(u3 & 0xFFFF0000u), w3, ay);
        }
        for (; j < cnt; ++j){
            int s = ssh[wid][j];
            float w = esh[wid][j][h];
            uint_t u = xp16[(size_t)s * 64 + l];
            ax = fmaf(__uint_as_float(u << 16), w, ax);
            ay = fmaf(__uint_as_float(u & 0xFFFF0000u), w, ay);
        }
    }

    float dh = sel4(d0, d1, d2, d3, h);
    float inv = 1.f / (dh + 1e-16f);
    float2 b2 = ((const float2*)bias)[l];
    float vx = ax * inv + b2.x;
    float vy = ay * inv + b2.y;
    vx = vx > 0.f ? vx : (__expf(vx) - 1.f);
    vy = vy > 0.f ? vy : (__expf(vy) - 1.f);

    if (mode == 0){
        ((float2*)hout)[(size_t)n * 64 + l] = make_float2(vx, vy);
    } else {
        float2 cw2 = ((const float2*)cW)[l];
        float p = vx * cw2.x + vy * cw2.y;
        p = wsum(p);
        if (l == 0){
            float logit = p + cb[0];
            fout[n] = 1.f / (1.f + __expf(-logit));
        }
    }
}

extern "C" void kernel_launch(void* const* d_in, const int* in_sizes, int n_in,
                              void* d_out, int out_size, void* d_ws, size_t ws_size,
                              hipStream_t stream){
    const float* x   = (const float*)d_in[0];
    const int*   ei  = (const int*)d_in[1];
    const float* W1  = (const float*)d_in[2];
    const float* as1 = (const float*)d_in[3];
    const float* ad1 = (const float*)d_in[4];
    const float* b1  = (const float*)d_in[5];
    const float* W2  = (const float*)d_in[6];
    const float* as2 = (const float*)d_in[7];
    const float* ad2 = (const float*)d_in[8];
    const float* b2  = (const float*)d_in[9];
    const float* W3  = (const float*)d_in[10];
    const float* as3 = (const float*)d_in[11];
    const float* ad3 = (const float*)d_in[12];
    const float* b3  = (const float*)d_in[13];
    const float* cW  = (const float*)d_in[14];
    const float* cb  = (const float*)d_in[15];
    float* out = (float*)d_out;

    int N = in_sizes[0] / 3;
    int E = in_sizes[1] / 2;
    int EN = E + N;

    char* ws = (char*)d_ws;
    size_t off = 0;
    auto alloc = [&](size_t bytes) -> void* {
        void* p = ws + off;
        off += (bytes + 255) & ~(size_t)255;
        return p;
    };
    int*    deg    = (int*)alloc((size_t)N * 4);
    int*    cursor = (int*)alloc((size_t)N * 4);
    int*    indptr = (int*)alloc((size_t)(N + 1) * 4);
    int*    srcs   = (int*)alloc((size_t)EN * 4);
    uint_t* XP     = (uint_t*)alloc((size_t)N * 64 * 4);   // packed bf16x2
    float*  H      = (float*)alloc((size_t)N * 128 * 4);
    float*  ALS    = (float*)alloc((size_t)N * 4 * 4);
    float*  ALD    = (float*)alloc((size_t)N * 4 * 4);
    int*    bsum   = (int*)alloc((size_t)1024 * 4);
    (void)ws_size;

    int NB = (N + 1023) / 1024;

    hipMemsetAsync(deg, 0, (size_t)N * 4, stream);
    hist_kernel<<<(EN + 255) / 256, 256, 0, stream>>>(ei, E, N, deg);
    scan_blocksum<<<NB, 256, 0, stream>>>(deg, bsum, N);
    scan_partials<<<1, 1024, 0, stream>>>(bsum, NB, indptr, N);
    scan_final<<<NB, 256, 0, stream>>>(deg, bsum, indptr, cursor, N);
    scatter_kernel<<<(EN + 255) / 256, 256, 0, stream>>>(ei, E, N, cursor, srcs);

    int ab = (N + 3) / 4;
    // layer 1 (K=3)
    linear_al<<<(N + 7) / 8, 128, 0, stream>>>(x, W1, as1, ad1, XP, ALS, ALD, N, 3);
    gat_agg2<<<ab, 256, 0, stream>>>(XP, (const float4*)ALS, (const float4*)ALD,
                                     indptr, srcs, b1, H, N, 0, nullptr, nullptr, nullptr);
    // layer 2
    gemm128_al<<<(N + 31) / 32, 256, 0, stream>>>(H, W2, as2, ad2, XP, ALS, ALD, N);
    gat_agg2<<<ab, 256, 0, stream>>>(XP, (const float4*)ALS, (const float4*)ALD,
                                     indptr, srcs, b2, H, N, 0, nullptr, nullptr, nullptr);
    // layer 3 + fused classifier
    gemm128_al<<<(N + 31) / 32, 256, 0, stream>>>(H, W3, as3, ad3, XP, ALS, ALD, N);
    gat_agg2<<<ab, 256, 0, stream>>>(XP, (const float4*)ALS, (const float4*)ALD,
                                     indptr, srcs, b3, nullptr, N, 1, cW, cb, out);
}

// Round 5
// 314.566 us; speedup vs baseline: 2.6810x; 1.0883x over previous
//
#include <hip/hip_runtime.h>
#include <math.h>

typedef unsigned int uint_t;

#define BK_SHIFT 7
#define BK_NODES 128
#define MAXBK 512          // supports N <= 65536
#define PART_CHUNK 4096
#define SORT_CAP 4096

__device__ __forceinline__ float lrelu(float x){ return x > 0.f ? x : 0.2f*x; }
__device__ __forceinline__ float sel4(float a, float b, float c, float d, int h){
    return h==0 ? a : (h==1 ? b : (h==2 ? c : d));
}
__device__ __forceinline__ float wmax(float v){
    #pragma unroll
    for (int m = 1; m < 64; m <<= 1) v = fmaxf(v, __shfl_xor(v, m));
    return v;
}
__device__ __forceinline__ float wsum(float v){
    #pragma unroll
    for (int m = 1; m < 64; m <<= 1) v += __shfl_xor(v, m);
    return v;
}
__device__ __forceinline__ uint_t pack_bf2(float a, float b){
    uint_t ua = __float_as_uint(a); uint_t ub = __float_as_uint(b);
    ua += 0x7FFFu + ((ua >> 16) & 1u);
    ub += 0x7FFFu + ((ub >> 16) & 1u);
    return (ua >> 16) | (ub & 0xFFFF0000u);
}

// ---------------- CSR build ----------------

__global__ void hist_kernel(const int* __restrict__ ei, int E, int N, int* __restrict__ deg){
    int idx = blockIdx.x * blockDim.x + threadIdx.x;
    if (idx >= E + N) return;
    int d = (idx < E) ? ei[E + idx] : (idx - E);
    atomicAdd(&deg[d], 1);
}

__global__ __launch_bounds__(256) void scan_blocksum(const int* __restrict__ deg,
                                                     int* __restrict__ bsum, int N){
    int b = blockIdx.x, t = threadIdx.x;
    int base = b * 1024 + t * 4;
    int s = 0;
    #pragma unroll
    for (int i = 0; i < 4; ++i){ int idx = base + i; if (idx < N) s += deg[idx]; }
    __shared__ int sm[256];
    sm[t] = s; __syncthreads();
    for (int off = 128; off > 0; off >>= 1){
        if (t < off) sm[t] += sm[t + off];
        __syncthreads();
    }
    if (t == 0) bsum[b] = sm[0];
}

__global__ __launch_bounds__(1024) void scan_partials(int* __restrict__ bsum, int NB,
                                                      int* __restrict__ indptr, int N){
    int t = threadIdx.x;
    int v = (t < NB) ? bsum[t] : 0;
    __shared__ int sm[1024];
    sm[t] = v; __syncthreads();
    for (int off = 1; off < 1024; off <<= 1){
        int u = (t >= off) ? sm[t - off] : 0;
        __syncthreads();
        sm[t] += u;
        __syncthreads();
    }
    if (t < NB) bsum[t] = (t == 0) ? 0 : sm[t - 1];
    if (t == NB - 1) indptr[N] = sm[t];
}

__global__ __launch_bounds__(256) void scan_final(const int* __restrict__ deg,
                                                  const int* __restrict__ bsum,
                                                  int* __restrict__ indptr, int N){
    int b = blockIdx.x, t = threadIdx.x;
    int base = b * 1024 + t * 4;
    int v0 = 0, v1 = 0, v2 = 0, v3 = 0;
    if (base + 0 < N) v0 = deg[base + 0];
    if (base + 1 < N) v1 = deg[base + 1];
    if (base + 2 < N) v2 = deg[base + 2];
    if (base + 3 < N) v3 = deg[base + 3];
    int s = v0 + v1 + v2 + v3;
    __shared__ int sm[256];
    sm[t] = s; __syncthreads();
    for (int off = 1; off < 256; off <<= 1){
        int u = (t >= off) ? sm[t - off] : 0;
        __syncthreads();
        sm[t] += u;
        __syncthreads();
    }
    int run = bsum[b] + ((t == 0) ? 0 : sm[t - 1]);
    if (base + 0 < N){ indptr[base + 0] = run; run += v0; }
    if (base + 1 < N){ indptr[base + 1] = run; run += v1; }
    if (base + 2 < N){ indptr[base + 2] = run; run += v2; }
    if (base + 3 < N){ indptr[base + 3] = run; run += v3; }
}

// gcursor[b] = indptr[b*128]
__global__ void bucket_init(const int* __restrict__ indptr, int* __restrict__ gcursor, int NBK){
    int b = blockIdx.x * blockDim.x + threadIdx.x;
    if (b < NBK) gcursor[b] = indptr[b << BK_SHIFT];
}

// phase A: partition (src,dst) pairs into bucket-contiguous pairbuf, coalesced runs
__global__ __launch_bounds__(256) void partition_kernel(
        const int* __restrict__ ei, int E, int N,
        int* __restrict__ gcursor, uint2* __restrict__ pairbuf, int NBK){
    __shared__ int hist[MAXBK];
    __shared__ int sA[MAXBK];
    __shared__ int sB[MAXBK];
    __shared__ int destadj[MAXBK];
    __shared__ int cnt2[MAXBK];
    __shared__ uint2 staged[PART_CHUNK];
    int t = threadIdx.x;
    int base = blockIdx.x * PART_CHUNK;
    int total = E + N;
    int cnt = total - base; if (cnt > PART_CHUNK) cnt = PART_CHUNK; if (cnt < 0) cnt = 0;

    for (int i = t; i < MAXBK; i += 256){ hist[i] = 0; cnt2[i] = 0; }
    __syncthreads();
    for (int i = t; i < cnt; i += 256){
        int idx = base + i;
        int d = (idx < E) ? ei[E + idx] : (idx - E);
        atomicAdd(&hist[d >> BK_SHIFT], 1);
    }
    __syncthreads();
    // inclusive scan of hist over MAXBK via ping-pong (2 elems/thread)
    sA[t] = hist[t]; sA[t + 256] = hist[t + 256];
    __syncthreads();
    int* psrc = sA; int* pdst = sB;
    for (int off = 1; off < MAXBK; off <<= 1){
        int i0 = t, i1 = t + 256;
        pdst[i0] = pdst[i1] = 0;
        pdst[i0] = psrc[i0] + ((i0 >= off) ? psrc[i0 - off] : 0);
        pdst[i1] = psrc[i1] + ((i1 >= off) ? psrc[i1 - off] : 0);
        __syncthreads();
        int* tmp = psrc; psrc = pdst; pdst = tmp;
    }
    // exclusive start of bucket b within staged = psrc[b-1]
    // reserve global runs
    for (int b = t; b < NBK; b += 256){
        int c = hist[b];
        int gstart = (b == 0) ? 0 : psrc[b - 1];
        int rbase = c > 0 ? atomicAdd(&gcursor[b], c) : 0;
        destadj[b] = rbase - gstart;
        cnt2[b] = gstart;       // running cursor starts at group start
    }
    __syncthreads();
    // stage grouped by bucket
    for (int i = t; i < cnt; i += 256){
        int idx = base + i;
        int d, s;
        if (idx < E){ s = ei[idx]; d = ei[E + idx]; }
        else        { s = d = idx - E; }
        int b = d >> BK_SHIFT;
        int pos = atomicAdd(&cnt2[b], 1);
        staged[pos] = make_uint2((uint_t)s, (uint_t)d);
    }
    __syncthreads();
    // coalesced-ish write out
    for (int p = t; p < cnt; p += 256){
        uint2 pr = staged[p];
        int b = (int)(pr.y >> BK_SHIFT);
        pairbuf[destadj[b] + p] = pr;
    }
}

// phase B: per-bucket counting sort into final CSR srcs (coalesced write)
__global__ __launch_bounds__(256) void bucket_sort_kernel(
        const uint2* __restrict__ pairbuf, const int* __restrict__ indptr,
        int* __restrict__ srcs, int N, int NBK){
    int b = blockIdx.x;
    int nb = b << BK_SHIFT;
    int nend = nb + BK_NODES; if (nend > N) nend = N;
    int beg = indptr[nb], end = indptr[nend];
    int cnt = end - beg;
    __shared__ int lptr[BK_NODES];
    __shared__ int outb[SORT_CAP];
    int t = threadIdx.x;
    if (t < BK_NODES){
        int node = nb + t;
        lptr[t] = (node < N) ? (indptr[node] - beg) : 0;
    }
    __syncthreads();
    if (cnt <= SORT_CAP){
        for (int i = t; i < cnt; i += 256){
            uint2 pr = pairbuf[beg + i];
            int pos = atomicAdd(&lptr[(int)(pr.y & (BK_NODES - 1))], 1);
            outb[pos] = (int)pr.x;
        }
        __syncthreads();
        for (int i = t; i < cnt; i += 256) srcs[beg + i] = outb[i];
    } else {
        for (int i = t; i < cnt; i += 256){
            uint2 pr = pairbuf[beg + i];
            int pos = atomicAdd(&lptr[(int)(pr.y & (BK_NODES - 1))], 1);
            srcs[beg + pos] = (int)pr.x;
        }
    }
}

// ---------------- layer-1 linear (K=3): xp packed bf16x2 ----------------
__global__ __launch_bounds__(128) void linear_al(
        const float* __restrict__ in, const float* __restrict__ W,
        const float* __restrict__ as_, const float* __restrict__ ad_,
        uint_t* __restrict__ xp16, float* __restrict__ als, float* __restrict__ ald,
        int N, int K){
    __shared__ float hs[8 * 3];
    int t = threadIdx.x;
    int base = blockIdx.x * 8;
    int rows = N - base; if (rows > 8) rows = 8;
    for (int idx = t; idx < rows * K; idx += 128){
        int r = idx / K, k = idx - r * K;
        hs[r * K + k] = in[(size_t)(base + r) * K + k];
    }
    __syncthreads();
    float acc[8] = {0.f,0.f,0.f,0.f,0.f,0.f,0.f,0.f};
    for (int k = 0; k < K; ++k){
        float w = W[k * 128 + t];
        #pragma unroll
        for (int r = 0; r < 8; ++r) acc[r] += hs[r * K + k] * w;
    }
    float asv = as_[t], adv = ad_[t];
    for (int r = 0; r < rows; ++r){
        int row = base + r;
        float v = acc[r];
        float vo = __shfl_xor(v, 1);
        if (!(t & 1)) xp16[(size_t)row * 64 + (t >> 1)] = pack_bf2(v, vo);
        float vs = v * asv, vd = v * adv;
        #pragma unroll
        for (int m = 16; m >= 1; m >>= 1){
            vs += __shfl_xor(vs, m);
            vd += __shfl_xor(vd, m);
        }
        if ((t & 31) == 0){
            int h = t >> 5;
            als[row * 4 + h] = vs;
            ald[row * 4 + h] = vd;
        }
    }
}

// ---------------- K=128 linear: register-tiled fp32 GEMM + fused als/ald ----------------
__global__ __launch_bounds__(256) void gemm128_al(
        const float* __restrict__ in, const float* __restrict__ W,
        const float* __restrict__ as_, const float* __restrict__ ad_,
        uint_t* __restrict__ xp16, float* __restrict__ als, float* __restrict__ ald,
        int N){
    __shared__ float Xs[32][128];
    int t = threadIdx.x;
    int base = blockIdx.x * 32;
    int rows = N - base; if (rows > 32) rows = 32;
    for (int f = t; f < 1024; f += 256){
        int r = f >> 5, q = f & 31;
        float4 v = (r < rows) ? ((const float4*)(in + (size_t)(base + r) * 128))[q]
                              : make_float4(0.f,0.f,0.f,0.f);
        ((float4*)Xs)[f] = v;
    }
    __syncthreads();
    int cg = t & 31;
    int rg = t >> 5;
    float acc[4][4];
    #pragma unroll
    for (int i = 0; i < 4; ++i)
        #pragma unroll
        for (int j = 0; j < 4; ++j) acc[i][j] = 0.f;

    const float4* W4 = (const float4*)W;
    for (int k4 = 0; k4 < 32; ++k4){
        float4 w0 = W4[(4*k4+0)*32 + cg];
        float4 w1 = W4[(4*k4+1)*32 + cg];
        float4 w2 = W4[(4*k4+2)*32 + cg];
        float4 w3 = W4[(4*k4+3)*32 + cg];
        #pragma unroll
        for (int i = 0; i < 4; ++i){
            float4 xv = ((const float4*)(&Xs[4*rg + i][0]))[k4];
            acc[i][0] = fmaf(xv.x, w0.x, acc[i][0]);
            acc[i][0] = fmaf(xv.y, w1.x, acc[i][0]);
            acc[i][0] = fmaf(xv.z, w2.x, acc[i][0]);
            acc[i][0] = fmaf(xv.w, w3.x, acc[i][0]);
            acc[i][1] = fmaf(xv.x, w0.y, acc[i][1]);
            acc[i][1] = fmaf(xv.y, w1.y, acc[i][1]);
            acc[i][1] = fmaf(xv.z, w2.y, acc[i][1]);
            acc[i][1] = fmaf(xv.w, w3.y, acc[i][1]);
            acc[i][2] = fmaf(xv.x, w0.z, acc[i][2]);
            acc[i][2] = fmaf(xv.y, w1.z, acc[i][2]);
            acc[i][2] = fmaf(xv.z, w2.z, acc[i][2]);
            acc[i][2] = fmaf(xv.w, w3.z, acc[i][2]);
            acc[i][3] = fmaf(xv.x, w0.w, acc[i][3]);
            acc[i][3] = fmaf(xv.y, w1.w, acc[i][3]);
            acc[i][3] = fmaf(xv.z, w2.w, acc[i][3]);
            acc[i][3] = fmaf(xv.w, w3.w, acc[i][3]);
        }
    }

    float4 as4 = ((const float4*)as_)[cg];
    float4 ad4 = ((const float4*)ad_)[cg];
    #pragma unroll
    for (int i = 0; i < 4; ++i){
        int r = 4*rg + i;
        if (r < rows){
            int row = base + r;
            uint2 pk;
            pk.x = pack_bf2(acc[i][0], acc[i][1]);
            pk.y = pack_bf2(acc[i][2], acc[i][3]);
            ((uint2*)xp16)[(size_t)row * 32 + cg] = pk;
            float ps = acc[i][0]*as4.x + acc[i][1]*as4.y + acc[i][2]*as4.z + acc[i][3]*as4.w;
            float pd = acc[i][0]*ad4.x + acc[i][1]*ad4.y + acc[i][2]*ad4.z + acc[i][3]*ad4.w;
            ps += __shfl_xor(ps, 1); ps += __shfl_xor(ps, 2); ps += __shfl_xor(ps, 4);
            pd += __shfl_xor(pd, 1); pd += __shfl_xor(pd, 2); pd += __shfl_xor(pd, 4);
            if ((cg & 7) == 0){
                int h = cg >> 3;
                als[(size_t)row * 4 + h] = ps;
                ald[(size_t)row * 4 + h] = pd;
            }
        }
    }
}

// ---------------- per-node softmax aggregation: one WAVE per node ----------------
__global__ __launch_bounds__(256) void gat_agg2(
        const uint_t* __restrict__ xp16, const float4* __restrict__ als,
        const float4* __restrict__ ald,
        const int* __restrict__ indptr, const int* __restrict__ srcs,
        const float* __restrict__ bias,
        float* __restrict__ hout, int N, int mode,
        const float* __restrict__ cW, const float* __restrict__ cb,
        float* __restrict__ fout){
    int wid = threadIdx.x >> 6;
    int l   = threadIdx.x & 63;
    int n = blockIdx.x * 4 + wid;
    __shared__ int   ssh[4][64];
    __shared__ float esh[4][64][4];
    if (n >= N) return;

    int beg = indptr[n], end = indptr[n + 1];
    float4 ad4 = ald[n];
    int h = l >> 4;

    float m0 = -INFINITY, m1 = -INFINITY, m2 = -INFINITY, m3 = -INFINITY;
    float d0 = 0.f, d1 = 0.f, d2 = 0.f, d3 = 0.f;
    float ax = 0.f, ay = 0.f;

    for (int cbeg = beg; cbeg < end; cbeg += 64){
        int cnt = end - cbeg; if (cnt > 64) cnt = 64;
        float e0 = -INFINITY, e1 = -INFINITY, e2 = -INFINITY, e3 = -INFINITY;
        if (l < cnt){
            int s = srcs[cbeg + l];
            ssh[wid][l] = s;
            float4 a4 = als[s];
            e0 = lrelu(a4.x + ad4.x);
            e1 = lrelu(a4.y + ad4.y);
            e2 = lrelu(a4.z + ad4.z);
            e3 = lrelu(a4.w + ad4.w);
        }
        float c0 = wmax(e0), c1 = wmax(e1), c2 = wmax(e2), c3 = wmax(e3);
        float nm0 = fmaxf(m0, c0), nm1 = fmaxf(m1, c1);
        float nm2 = fmaxf(m2, c2), nm3 = fmaxf(m3, c3);
        float r0 = __expf(m0 - nm0), r1 = __expf(m1 - nm1);
        float r2 = __expf(m2 - nm2), r3 = __expf(m3 - nm3);
        d0 *= r0; d1 *= r1; d2 *= r2; d3 *= r3;
        float rh = sel4(r0, r1, r2, r3, h);
        ax *= rh; ay *= rh;
        m0 = nm0; m1 = nm1; m2 = nm2; m3 = nm3;

        float p0 = 0.f, p1 = 0.f, p2 = 0.f, p3 = 0.f;
        if (l < cnt){
            p0 = __expf(e0 - m0);
            p1 = __expf(e1 - m1);
            p2 = __expf(e2 - m2);
            p3 = __expf(e3 - m3);
            *((float4*)&esh[wid][l][0]) = make_float4(p0, p1, p2, p3);
        }
        d0 += wsum(p0); d1 += wsum(p1); d2 += wsum(p2); d3 += wsum(p3);

        int j = 0;
        for (; j + 4 <= cnt; j += 4){
            int s0 = ssh[wid][j+0]; float w0 = esh[wid][j+0][h];
            int s1 = ssh[wid][j+1]; float w1 = esh[wid][j+1][h];
            int s2 = ssh[wid][j+2]; float w2 = esh[wid][j+2][h];
            int s3 = ssh[wid][j+3]; float w3 = esh[wid][j+3][h];
            uint_t u0 = xp16[(size_t)s0 * 64 + l];
            uint_t u1 = xp16[(size_t)s1 * 64 + l];
            uint_t u2 = xp16[(size_t)s2 * 64 + l];
            uint_t u3 = xp16[(size_t)s3 * 64 + l];
            ax = fmaf(__uint_as_float(u0 << 16), w0, ax);
            ay = fmaf(__uint_as_float(u0 & 0xFFFF0000u), w0, ay);
            ax = fmaf(__uint_as_float(u1 << 16), w1, ax);
            ay = fmaf(__uint_as_float(u1 & 0xFFFF0000u), w1, ay);
            ax = fmaf(__uint_as_float(u2 << 16), w2, ax);
            ay = fmaf(__uint_as_float(u2 & 0xFFFF0000u), w2, ay);
            ax = fmaf(__uint_as_float(u3 << 16), w3, ax);
            ay = fmaf(__uint_as_float(u3 & 0xFFFF0000u), w3, ay);
        }
        for (; j < cnt; ++j){
            int s = ssh[wid][j];
            float w = esh[wid][j][h];
            uint_t u = xp16[(size_t)s * 64 + l];
            ax = fmaf(__uint_as_float(u << 16), w, ax);
            ay = fmaf(__uint_as_float(u & 0xFFFF0000u), w, ay);
        }
    }

    float dh = sel4(d0, d1, d2, d3, h);
    float inv = 1.f / (dh + 1e-16f);
    float2 b2 = ((const float2*)bias)[l];
    float vx = ax * inv + b2.x;
    float vy = ay * inv + b2.y;
    vx = vx > 0.f ? vx : (__expf(vx) - 1.f);
    vy = vy > 0.f ? vy : (__expf(vy) - 1.f);

    if (mode == 0){
        ((float2*)hout)[(size_t)n * 64 + l] = make_float2(vx, vy);
    } else {
        float2 cw2 = ((const float2*)cW)[l];
        float p = vx * cw2.x + vy * cw2.y;
        p = wsum(p);
        if (l == 0){
            float logit = p + cb[0];
            fout[n] = 1.f / (1.f + __expf(-logit));
        }
    }
}

extern "C" void kernel_launch(void* const* d_in, const int* in_sizes, int n_in,
                              void* d_out, int out_size, void* d_ws, size_t ws_size,
                              hipStream_t stream){
    const float* x   = (const float*)d_in[0];
    const int*   ei  = (const int*)d_in[1];
    const float* W1  = (const float*)d_in[2];
    const float* as1 = (const float*)d_in[3];
    const float* ad1 = (const float*)d_in[4];
    const float* b1  = (const float*)d_in[5];
    const float* W2  = (const float*)d_in[6];
    const float* as2 = (const float*)d_in[7];
    const float* ad2 = (const float*)d_in[8];
    const float* b2  = (const float*)d_in[9];
    const float* W3  = (const float*)d_in[10];
    const float* as3 = (const float*)d_in[11];
    const float* ad3 = (const float*)d_in[12];
    const float* b3  = (const float*)d_in[13];
    const float* cW  = (const float*)d_in[14];
    const float* cb  = (const float*)d_in[15];
    float* out = (float*)d_out;

    int N = in_sizes[0] / 3;
    int E = in_sizes[1] / 2;
    int EN = E + N;
    int NBK = (N + BK_NODES - 1) / BK_NODES;

    char* ws = (char*)d_ws;
    size_t off = 0;
    auto alloc = [&](size_t bytes) -> void* {
        void* p = ws + off;
        off += (bytes + 255) & ~(size_t)255;
        return p;
    };
    int*    deg     = (int*)alloc((size_t)N * 4);
    int*    indptr  = (int*)alloc((size_t)(N + 1) * 4);
    int*    srcs    = (int*)alloc((size_t)EN * 4);
    uint2*  pairbuf = (uint2*)alloc((size_t)EN * 8);
    uint_t* XP      = (uint_t*)alloc((size_t)N * 64 * 4);
    float*  H       = (float*)alloc((size_t)N * 128 * 4);
    float*  ALS     = (float*)alloc((size_t)N * 4 * 4);
    float*  ALD     = (float*)alloc((size_t)N * 4 * 4);
    int*    bsum    = (int*)alloc((size_t)1024 * 4);
    int*    gcursor = (int*)alloc((size_t)MAXBK * 4);
    (void)ws_size;

    int NB = (N + 1023) / 1024;

    hipMemsetAsync(deg, 0, (size_t)N * 4, stream);
    hist_kernel<<<(EN + 255) / 256, 256, 0, stream>>>(ei, E, N, deg);
    scan_blocksum<<<NB, 256, 0, stream>>>(deg, bsum, N);
    scan_partials<<<1, 1024, 0, stream>>>(bsum, NB, indptr, N);
    scan_final<<<NB, 256, 0, stream>>>(deg, bsum, indptr, N);
    bucket_init<<<(NBK + 255) / 256, 256, 0, stream>>>(indptr, gcursor, NBK);
    partition_kernel<<<(EN + PART_CHUNK - 1) / PART_CHUNK, 256, 0, stream>>>(
        ei, E, N, gcursor, pairbuf, NBK);
    bucket_sort_kernel<<<NBK, 256, 0, stream>>>(pairbuf, indptr, srcs, N, NBK);

    int ab = (N + 3) / 4;
    // layer 1 (K=3)
    linear_al<<<(N + 7) / 8, 128, 0, stream>>>(x, W1, as1, ad1, XP, ALS, ALD, N, 3);
    gat_agg2<<<ab, 256, 0, stream>>>(XP, (const float4*)ALS, (const float4*)ALD,
                                     indptr, srcs, b1, H, N, 0, nullptr, nullptr, nullptr);
    // layer 2
    gemm128_al<<<(N + 31) / 32, 256, 0, stream>>>(H, W2, as2, ad2, XP, ALS, ALD, N);
    gat_agg2<<<ab, 256, 0, stream>>>(XP, (const float4*)ALS, (const float4*)ALD,
                                     indptr, srcs, b2, H, N, 0, nullptr, nullptr, nullptr);
    // layer 3 + fused classifier
    gemm128_al<<<(N + 31) / 32, 256, 0, stream>>>(H, W3, as3, ad3, XP, ALS, ALD, N);
    gat_agg2<<<ab, 256, 0, stream>>>(XP, (const float4*)ALS, (const float4*)ALD,
                                     indptr, srcs, b3, nullptr, N, 1, cW, cb, out);
}